// Round 1
// baseline (352.006 us; speedup 1.0000x reference)
//
#include <hip/hip_runtime.h>
#include <stdint.h>

// Problem constants: B=4, S=2048, D=1024, H=8, DK=128, C=128
typedef __attribute__((ext_vector_type(8))) short short8;
typedef __attribute__((ext_vector_type(4))) float floatx4;

__device__ __forceinline__ unsigned short f2bf(float f) {
  union { float f; uint32_t u; } v; v.f = f;
  return (unsigned short)((v.u + 0x7fffu + ((v.u >> 16) & 1u)) >> 16);
}

// ---- detect mask element width (int32 vs uint8) ----------------------------
__global__ void k_detect(const uint32_t* __restrict__ m, int* __restrict__ flag) {
  __shared__ int any;
  if (threadIdx.x == 0) any = 0;
  __syncthreads();
  int a = 0;
  for (int i = threadIdx.x; i < 16384; i += 256) a |= (m[i] > 1u) ? 1 : 0;
  if (a) atomicOr(&any, 1);
  __syncthreads();
  if (threadIdx.x == 0) *flag = any;   // 1 => bytes (uint8/bool), 0 => int32
}

// ---- bit-pack mask: bits[b][q][s/64], bit s = masked ------------------------
__global__ void k_bitpack(const void* __restrict__ mask, const int* __restrict__ flag,
                          unsigned long long* __restrict__ bits) {
  long tid = (long)blockIdx.x * 256 + threadIdx.x;   // (b*2048+q)*2048+s
  int f = *flag;
  int v = f ? (int)((const uint8_t*)mask)[tid] : ((const int*)mask)[tid];
  unsigned long long b = __ballot(v != 0);
  if ((threadIdx.x & 63) == 0) bits[tid >> 6] = b;
}

// ---- x (f32) -> bf16 --------------------------------------------------------
__global__ void k_cvt_x(const float4* __restrict__ x, uint2* __restrict__ xbf) {
  long i = (long)blockIdx.x * 256 + threadIdx.x;
  float4 v = x[i];
  uint2 o;
  o.x = (uint32_t)f2bf(v.x) | ((uint32_t)f2bf(v.y) << 16);
  o.y = (uint32_t)f2bf(v.z) | ((uint32_t)f2bf(v.w) << 16);
  xbf[i] = o;
}

// ---- W_q,W_k [H,D,DK] -> wqkt[2048][1024] bf16, row n = output feature -----
__global__ void k_cvt_w(const float* __restrict__ wq, const float* __restrict__ wk,
                        unsigned short* __restrict__ wqkt) {
  int tid = blockIdx.x * 256 + threadIdx.x;   // n*1024 + d
  int n = tid >> 10, d = tid & 1023;
  const float* src = (n < 1024) ? wq : wk;
  int nn = n & 1023;
  int h = nn >> 7, dk = nn & 127;
  wqkt[tid] = f2bf(src[h * 131072 + d * 128 + dk]);
}

// ---- GEMM: qk[8192][2048] = xbf[8192][1024] * wqkt[2048][1024]^T (bf16 out) -
__launch_bounds__(256, 2)
__global__ void k_gemm_qk(const unsigned short* __restrict__ xbf,
                          const unsigned short* __restrict__ wqkt,
                          unsigned short* __restrict__ qk) {
  __shared__ uint4 a4[1024];   // 16 subtiles (mi,ki), fragment-order, 16KB
  __shared__ uint4 b4[1024];
  const unsigned short* al = (const unsigned short*)a4;
  const unsigned short* bl = (const unsigned short*)b4;
  int bx = blockIdx.x;
  int m0 = (bx >> 4) * 128, n0 = (bx & 15) * 128;
  int t = threadIdx.x, w = t >> 6, l = t & 63;
  int lr = l & 15, lc = l >> 4;
  int wr = w >> 1, wc = w & 1;
  floatx4 z = {0.f, 0.f, 0.f, 0.f};
  floatx4 acc[4][4];
#pragma unroll
  for (int ii = 0; ii < 4; ii++)
#pragma unroll
    for (int jj = 0; jj < 4; jj++) acc[ii][jj] = z;

  for (int k0 = 0; k0 < 1024; k0 += 64) {
    __syncthreads();
    uint4 tmp[8];
#pragma unroll
    for (int j = 0; j < 8; j++) {
      int s = w * 8 + j;
      const unsigned short* src;
      if (s < 16) { int mi = s >> 1, ki = s & 1;
        src = xbf + (m0 + mi * 16 + lr) * 1024 + k0 + ki * 32 + lc * 8;
      } else { int s2 = s - 16, ni = s2 >> 1, ki = s2 & 1;
        src = wqkt + (n0 + ni * 16 + lr) * 1024 + k0 + ki * 32 + lc * 8;
      }
      tmp[j] = *(const uint4*)src;
    }
#pragma unroll
    for (int j = 0; j < 8; j++) {
      int s = w * 8 + j;
      uint4* dst = (s < 16) ? (a4 + s * 64 + l) : (b4 + (s - 16) * 64 + l);
      *dst = tmp[j];
    }
    __syncthreads();
#pragma unroll
    for (int ki = 0; ki < 2; ki++) {
      short8 af[4], bfr[4];
#pragma unroll
      for (int mf = 0; mf < 4; mf++)
        af[mf] = *(const short8*)(al + ((wr * 4 + mf) * 2 + ki) * 512 + l * 8);
#pragma unroll
      for (int nf = 0; nf < 4; nf++)
        bfr[nf] = *(const short8*)(bl + ((wc * 4 + nf) * 2 + ki) * 512 + l * 8);
#pragma unroll
      for (int mf = 0; mf < 4; mf++)
#pragma unroll
        for (int nf = 0; nf < 4; nf++)
          acc[mf][nf] = __builtin_amdgcn_mfma_f32_16x16x32_bf16(af[mf], bfr[nf], acc[mf][nf], 0, 0, 0);
    }
  }
#pragma unroll
  for (int mf = 0; mf < 4; mf++)
#pragma unroll
    for (int nf = 0; nf < 4; nf++)
#pragma unroll
      for (int i = 0; i < 4; i++) {
        int row = m0 + wr * 64 + mf * 16 + lc * 4 + i;
        int col = n0 + wc * 64 + nf * 16 + lr;
        qk[(long)row * 2048 + col] = f2bf(acc[mf][nf][i]);
      }
}

// ---- attention: abar[h*4+b][s] = mean_q softmax(QK^T/scale, mask) -----------
// Two passes over keys per 128-query block: pass1 row sums l (no max-sub:
// logits ~N(0,0.41), exp never overflows f32); pass2 accumulates column sums.
__launch_bounds__(256, 2)
__global__ void k_attn(const unsigned short* __restrict__ qk,
                       const unsigned long long* __restrict__ bits,
                       float* __restrict__ abar) {
  __shared__ uint4 k4[1024];                 // K tile 64x128 bf16, 16KB
  __shared__ unsigned long long mw[128];     // mask words, this key-step
  __shared__ float colacc[2048];
  const unsigned short* kl = (const unsigned short*)k4;
  int qb = blockIdx.x, b = blockIdx.y, h = blockIdx.z;
  int t = threadIdx.x, w = t >> 6, l = t & 63;
  int lr = l & 15, lc = l >> 4;
  int q0 = qb * 128;
  const unsigned short* Q = qk + (long)b * 2048 * 2048 + h * 128;
  const unsigned short* K = qk + (long)b * 2048 * 2048 + 1024 + h * 128;
  const unsigned long long* brow = bits + ((long)b * 2048 + q0) * 32;

  for (int s = t; s < 2048; s += 256) colacc[s] = 0.f;

  short8 qf[2][4];   // Q fragments direct from global (no LDS needed)
#pragma unroll
  for (int mf = 0; mf < 2; mf++)
#pragma unroll
    for (int ki = 0; ki < 4; ki++)
      qf[mf][ki] = *(const short8*)(Q + (long)(q0 + w * 32 + mf * 16 + lr) * 2048 + ki * 32 + lc * 8);

  const float rscale = 0.08838834764831845f;  // 1/sqrt(128)
  floatx4 z = {0.f, 0.f, 0.f, 0.f};
  float lsum[2][4] = {{0,0,0,0},{0,0,0,0}};

  // ---- PASS 1: row sums ----
  for (int s0 = 0; s0 < 2048; s0 += 64) {
    __syncthreads();
#pragma unroll
    for (int j = 0; j < 4; j++) {
      int sub = w * 4 + j, si = sub >> 2, ki = sub & 3;
      k4[sub * 64 + l] = *(const uint4*)(K + (long)(s0 + si * 16 + lr) * 2048 + ki * 32 + lc * 8);
    }
    if (t < 128) mw[t] = brow[(long)t * 32 + (s0 >> 6)];
    __syncthreads();
    floatx4 acc[2][4];
#pragma unroll
    for (int ii = 0; ii < 2; ii++)
#pragma unroll
      for (int jj = 0; jj < 4; jj++) acc[ii][jj] = z;
#pragma unroll
    for (int ki = 0; ki < 4; ki++) {
      short8 bb[4];
#pragma unroll
      for (int nf = 0; nf < 4; nf++) bb[nf] = *(const short8*)(kl + (nf * 4 + ki) * 512 + l * 8);
#pragma unroll
      for (int nf = 0; nf < 4; nf++) {
        acc[0][nf] = __builtin_amdgcn_mfma_f32_16x16x32_bf16(qf[0][ki], bb[nf], acc[0][nf], 0, 0, 0);
        acc[1][nf] = __builtin_amdgcn_mfma_f32_16x16x32_bf16(qf[1][ki], bb[nf], acc[1][nf], 0, 0, 0);
      }
    }
#pragma unroll
    for (int mf = 0; mf < 2; mf++)
#pragma unroll
      for (int i = 0; i < 4; i++) {
        unsigned long long wmk = mw[w * 32 + mf * 16 + lc * 4 + i] >> lr;
        float p = 0.f;
#pragma unroll
        for (int nf = 0; nf < 4; nf++) {
          float vv = acc[mf][nf][i] * rscale;
          p += ((wmk >> (nf * 16)) & 1ull) ? 0.f : __expf(vv);
        }
        lsum[mf][i] += p;
      }
  }
  float rinv[2][4];
#pragma unroll
  for (int mf = 0; mf < 2; mf++)
#pragma unroll
    for (int i = 0; i < 4; i++) {
      float v = lsum[mf][i];
      v += __shfl_xor(v, 1); v += __shfl_xor(v, 2);
      v += __shfl_xor(v, 4); v += __shfl_xor(v, 8);
      rinv[mf][i] = 1.f / (v * 2048.f);   // fold mean over q
    }
  // ---- PASS 2: column sums ----
  for (int s0 = 0; s0 < 2048; s0 += 64) {
    __syncthreads();
#pragma unroll
    for (int j = 0; j < 4; j++) {
      int sub = w * 4 + j, si = sub >> 2, ki = sub & 3;
      k4[sub * 64 + l] = *(const uint4*)(K + (long)(s0 + si * 16 + lr) * 2048 + ki * 32 + lc * 8);
    }
    if (t < 128) mw[t] = brow[(long)t * 32 + (s0 >> 6)];
    __syncthreads();
    floatx4 acc[2][4];
#pragma unroll
    for (int ii = 0; ii < 2; ii++)
#pragma unroll
      for (int jj = 0; jj < 4; jj++) acc[ii][jj] = z;
#pragma unroll
    for (int ki = 0; ki < 4; ki++) {
      short8 bb[4];
#pragma unroll
      for (int nf = 0; nf < 4; nf++) bb[nf] = *(const short8*)(kl + (nf * 4 + ki) * 512 + l * 8);
#pragma unroll
      for (int nf = 0; nf < 4; nf++) {
        acc[0][nf] = __builtin_amdgcn_mfma_f32_16x16x32_bf16(qf[0][ki], bb[nf], acc[0][nf], 0, 0, 0);
        acc[1][nf] = __builtin_amdgcn_mfma_f32_16x16x32_bf16(qf[1][ki], bb[nf], acc[1][nf], 0, 0, 0);
      }
    }
    float cp[4] = {0.f, 0.f, 0.f, 0.f};
#pragma unroll
    for (int mf = 0; mf < 2; mf++)
#pragma unroll
      for (int i = 0; i < 4; i++) {
        unsigned long long wmk = mw[w * 32 + mf * 16 + lc * 4 + i] >> lr;
        float ri = rinv[mf][i];
#pragma unroll
        for (int nf = 0; nf < 4; nf++) {
          float vv = acc[mf][nf][i] * rscale;
          cp[nf] += ((wmk >> (nf * 16)) & 1ull) ? 0.f : __expf(vv) * ri;
        }
      }
#pragma unroll
    for (int nf = 0; nf < 4; nf++) {
      float v = cp[nf];
      v += __shfl_xor(v, 16);
      v += __shfl_xor(v, 32);
      if (lc == 0) atomicAdd(&colacc[s0 + nf * 16 + lr], v);
    }
  }
  __syncthreads();
  float* ab = abar + ((h * 4 + b) << 11);
  for (int s = t; s < 2048; s += 256) atomicAdd(&ab[s], colacc[s]);
}

// ---- xbar[h*4+b][d] = sum_s abar[h,b,s] * x[b,s,d] -------------------------
__global__ void k_xbar(const float* __restrict__ x, const float* __restrict__ abar,
                       float* __restrict__ xbar) {
  __shared__ float ab[8][128];
  int bx = blockIdx.x;            // dc(4) * 16 + sc(16)
  int b = blockIdx.y;
  int dc = bx >> 4, sc = bx & 15;
  int t = threadIdx.x;
  int d = dc * 256 + t;
  int sc0 = sc * 128;
  for (int i = t; i < 1024; i += 256) {
    int hh = i >> 7, s = i & 127;
    ab[hh][s] = abar[(hh * 4 + b) * 2048 + sc0 + s];
  }
  __syncthreads();
  float acc[8] = {0,0,0,0,0,0,0,0};
  const float* xp = x + ((long)b * 2048 + sc0) * 1024 + d;
  for (int s = 0; s < 128; s++) {
    float xv = xp[(long)s * 1024];
#pragma unroll
    for (int hh = 0; hh < 8; hh++) acc[hh] += xv * ab[hh][s];
  }
#pragma unroll
  for (int hh = 0; hh < 8; hh++) atomicAdd(&xbar[(hh * 4 + b) * 1024 + d], acc[hh]);
}

// ---- ocat[b][h*128+k] = xbar[h,b,:] @ W_v[h][:,k] ---------------------------
__global__ void k_ov(const float* __restrict__ Wv, const float* __restrict__ xbar,
                     float* __restrict__ ocat) {
  __shared__ float xb[1024];
  int hb = blockIdx.x;   // h*4+b
  int h = hb >> 2, b = hb & 3;
  int k = threadIdx.x;   // 128
  for (int i = k; i < 1024; i += 128) xb[i] = xbar[hb * 1024 + i];
  __syncthreads();
  float acc = 0.f;
  const float* wp = Wv + (long)h * 131072 + k;
  for (int d = 0; d < 1024; d++) acc += xb[d] * wp[(long)d * 128];
  ocat[b * 1024 + h * 128 + k] = acc;
}

// ---- out1[b][d] = ocat[b,:] . W_lin[d,:] + b_lin[d] -------------------------
__global__ void k_lin(const float* __restrict__ ocat, const float* __restrict__ Wlin,
                      const float* __restrict__ blin, float* __restrict__ out1) {
  int gw = blockIdx.x * 4 + (threadIdx.x >> 6);   // 0..4095 = b*1024+d
  int l = threadIdx.x & 63;
  int b = gw >> 10, d = gw & 1023;
  const float* o = ocat + b * 1024;
  const float* wr = Wlin + (long)d * 1024;
  float acc = 0.f;
  for (int f = l; f < 1024; f += 64) acc += o[f] * wr[f];
#pragma unroll
  for (int m = 32; m; m >>= 1) acc += __shfl_xor(acc, m);
  if (l == 0) out1[gw] = acc + blin[d];
}

// ---- out[b][c] = out1[b,:] . W_last[c,:] + b_last[c] ------------------------
__global__ void k_last(const float* __restrict__ out1, const float* __restrict__ Wlast,
                       const float* __restrict__ blast, float* __restrict__ out) {
  int gw = blockIdx.x * 4 + (threadIdx.x >> 6);   // 0..511 = b*128+c
  int l = threadIdx.x & 63;
  int b = gw >> 7, c = gw & 127;
  const float* i1 = out1 + b * 1024;
  const float* wr = Wlast + (long)c * 1024;
  float acc = 0.f;
  for (int f = l; f < 1024; f += 64) acc += i1[f] * wr[f];
#pragma unroll
  for (int m = 32; m; m >>= 1) acc += __shfl_xor(acc, m);
  if (l == 0) out[gw] = acc + blast[c];
}

extern "C" void kernel_launch(void* const* d_in, const int* in_sizes, int n_in,
                              void* d_out, int out_size, void* d_ws, size_t ws_size,
                              hipStream_t stream) {
  const float* x     = (const float*)d_in[0];
  const void*  mask  = d_in[1];
  const float* Wq    = (const float*)d_in[2];
  const float* Wk    = (const float*)d_in[3];
  const float* Wv    = (const float*)d_in[4];
  const float* Wlin  = (const float*)d_in[5];
  const float* blin  = (const float*)d_in[6];
  const float* Wlast = (const float*)d_in[7];
  const float* blast = (const float*)d_in[8];
  float* out = (float*)d_out;

  char* ws = (char*)d_ws;
  // ws layout (bytes)
  const size_t OFF_FLAG = 0;                      // 256
  const size_t OFF_BITS = 256;                    // 2,097,152
  const size_t OFF_XBF  = 2097408;                // 16,777,216
  const size_t OFF_WQKT = 18874624;               // 4,194,304
  const size_t OFF_QK   = 23068928;               // 33,554,432
  const size_t OFF_ABAR = 56623360;               // 262,144
  const size_t OFF_XBAR = 56885504;               // 131,072
  const size_t OFF_OCAT = 57016576;               // 16,384
  const size_t OFF_OUT1 = 57032960;               // 16,384

  int* flag = (int*)(ws + OFF_FLAG);
  unsigned long long* bits = (unsigned long long*)(ws + OFF_BITS);
  unsigned short* xbf  = (unsigned short*)(ws + OFF_XBF);
  unsigned short* wqkt = (unsigned short*)(ws + OFF_WQKT);
  unsigned short* qkb  = (unsigned short*)(ws + OFF_QK);
  float* abar = (float*)(ws + OFF_ABAR);
  float* xbarp = (float*)(ws + OFF_XBAR);
  float* ocat = (float*)(ws + OFF_OCAT);
  float* out1 = (float*)(ws + OFF_OUT1);

  hipMemsetAsync(ws + OFF_ABAR, 0, 262144 + 131072, stream);  // abar + xbar
  k_detect<<<1, 256, 0, stream>>>((const uint32_t*)mask, flag);
  k_bitpack<<<65536, 256, 0, stream>>>(mask, flag, bits);
  k_cvt_x<<<8192, 256, 0, stream>>>((const float4*)x, (uint2*)xbf);
  k_cvt_w<<<8192, 256, 0, stream>>>(Wq, Wk, wqkt);
  k_gemm_qk<<<1024, 256, 0, stream>>>(xbf, wqkt, qkb);
  k_attn<<<dim3(16, 4, 8), 256, 0, stream>>>(qkb, bits, abar);
  k_xbar<<<dim3(64, 4), 256, 0, stream>>>(x, abar, xbarp);
  k_ov<<<32, 128, 0, stream>>>(Wv, xbarp, ocat);
  k_lin<<<1024, 256, 0, stream>>>(ocat, Wlin, blin, out1);
  k_last<<<128, 256, 0, stream>>>(out1, Wlast, blast, out);
}

// Round 3
// 328.312 us; speedup vs baseline: 1.0722x; 1.0722x over previous
//
#include <hip/hip_runtime.h>
#include <stdint.h>

// Problem constants: B=4, S=2048, D=1024, H=8, DK=128, C=128
typedef __attribute__((ext_vector_type(8))) short short8;
typedef __attribute__((ext_vector_type(4))) float floatx4;

#if defined(__has_builtin)
#if __has_builtin(__builtin_amdgcn_exp2f)
#define EXP2(x) __builtin_amdgcn_exp2f(x)
#endif
#endif
#ifndef EXP2
#define EXP2(x) exp2f(x)
#endif

// 1/sqrt(128) * log2(e)  — folded into W_q so softmax needs only v_exp_f32
#define WQ_SCALE (0.08838834764831845f * 1.4426950408889634f)

__device__ __forceinline__ unsigned short f2bf(float f) {
  union { float f; uint32_t u; } v; v.f = f;
  return (unsigned short)((v.u + 0x7fffu + ((v.u >> 16) & 1u)) >> 16);
}

// async global->LDS DMA, 16B per lane; dst must be wave-uniform base (lane*16 implicit)
__device__ __forceinline__ void gld_lds16(const void* g, void* l) {
  __builtin_amdgcn_global_load_lds((const __attribute__((address_space(1))) uint32_t*)g,
                                   (__attribute__((address_space(3))) uint32_t*)l, 16, 0, 0);
}

// ---- detect mask element width (int32 vs uint8) ----------------------------
__global__ void k_detect(const uint32_t* __restrict__ m, int* __restrict__ flag) {
  __shared__ int any;
  if (threadIdx.x == 0) any = 0;
  __syncthreads();
  int a = 0;
  for (int i = threadIdx.x; i < 16384; i += 256) a |= (m[i] > 1u) ? 1 : 0;
  if (a) atomicOr(&any, 1);
  __syncthreads();
  if (threadIdx.x == 0) *flag = any;   // 1 => bytes (uint8/bool), 0 => int32
}

// ---- bit-pack mask: bits[b][q][s/64], bit s = masked ------------------------
__global__ void k_bitpack(const void* __restrict__ mask, const int* __restrict__ flag,
                          unsigned long long* __restrict__ bits) {
  long tid = (long)blockIdx.x * 256 + threadIdx.x;   // (b*2048+q)*2048+s
  int f = *flag;
  int v = f ? (int)((const uint8_t*)mask)[tid] : ((const int*)mask)[tid];
  unsigned long long b = __ballot(v != 0);
  if ((threadIdx.x & 63) == 0) bits[tid >> 6] = b;
}

// ---- x (f32) -> bf16 --------------------------------------------------------
__global__ void k_cvt_x(const float4* __restrict__ x, uint2* __restrict__ xbf) {
  long i = (long)blockIdx.x * 256 + threadIdx.x;
  float4 v = x[i];
  uint2 o;
  o.x = (uint32_t)f2bf(v.x) | ((uint32_t)f2bf(v.y) << 16);
  o.y = (uint32_t)f2bf(v.z) | ((uint32_t)f2bf(v.w) << 16);
  xbf[i] = o;
}

// ---- W_q,W_k [H,D,DK] -> wqkt[2048][1024] bf16; W_q pre-scaled --------------
__global__ void k_cvt_w(const float* __restrict__ wq, const float* __restrict__ wk,
                        unsigned short* __restrict__ wqkt) {
  int tid = blockIdx.x * 256 + threadIdx.x;   // n*1024 + d
  int n = tid >> 10, d = tid & 1023;
  int isq = (n < 1024);
  const float* src = isq ? wq : wk;
  int nn = n & 1023;
  int h = nn >> 7, dk = nn & 127;
  float v = src[h * 131072 + d * 128 + dk];
  wqkt[tid] = f2bf(isq ? v * WQ_SCALE : v);
}

// ---- GEMM: qk[8192][2048] = xbf[8192][1024] * wqkt[2048][1024]^T (bf16 out) -
__launch_bounds__(256, 2)
__global__ void k_gemm_qk(const unsigned short* __restrict__ xbf,
                          const unsigned short* __restrict__ wqkt,
                          unsigned short* __restrict__ qk) {
  __shared__ uint4 ab4[2048];   // 32KB: A subtiles 0..15, B subtiles 16..31, fragment-order
  const unsigned short* al = (const unsigned short*)ab4;
  const unsigned short* bl = al + 8192;   // B at BYTE 16384 (= subtile 16 * 1024B)
  int bx = blockIdx.x;
  int m0 = (bx >> 4) * 128, n0 = (bx & 15) * 128;
  int t = threadIdx.x, w = t >> 6, l = t & 63;
  int lr = l & 15, lc = l >> 4;
  int wr = w >> 1, wc = w & 1;
  floatx4 z = {0.f, 0.f, 0.f, 0.f};
  floatx4 acc[4][4];
#pragma unroll
  for (int ii = 0; ii < 4; ii++)
#pragma unroll
    for (int jj = 0; jj < 4; jj++) acc[ii][jj] = z;

  for (int k0 = 0; k0 < 1024; k0 += 64) {
    __syncthreads();
#pragma unroll
    for (int j = 0; j < 8; j++) {
      int s = w * 8 + j;
      const unsigned short* src;
      if (s < 16) { int mi = s >> 1, ki = s & 1;
        src = xbf + (long)(m0 + mi * 16 + lr) * 1024 + k0 + ki * 32 + lc * 8;
      } else { int s2 = s - 16, ni = s2 >> 1, ki = s2 & 1;
        src = wqkt + (long)(n0 + ni * 16 + lr) * 1024 + k0 + ki * 32 + lc * 8;
      }
      gld_lds16(src, ab4 + s * 64);
    }
    __syncthreads();
#pragma unroll
    for (int ki = 0; ki < 2; ki++) {
      short8 af[4], bfr[4];
#pragma unroll
      for (int mf = 0; mf < 4; mf++)
        af[mf] = *(const short8*)(al + ((wr * 4 + mf) * 2 + ki) * 512 + l * 8);
#pragma unroll
      for (int nf = 0; nf < 4; nf++)
        bfr[nf] = *(const short8*)(bl + ((wc * 4 + nf) * 2 + ki) * 512 + l * 8);
#pragma unroll
      for (int mf = 0; mf < 4; mf++)
#pragma unroll
        for (int nf = 0; nf < 4; nf++)
          acc[mf][nf] = __builtin_amdgcn_mfma_f32_16x16x32_bf16(af[mf], bfr[nf], acc[mf][nf], 0, 0, 0);
    }
  }
#pragma unroll
  for (int mf = 0; mf < 4; mf++)
#pragma unroll
    for (int nf = 0; nf < 4; nf++)
#pragma unroll
      for (int i = 0; i < 4; i++) {
        int row = m0 + wr * 64 + mf * 16 + lc * 4 + i;
        int col = n0 + wc * 64 + nf * 16 + lr;
        qk[(long)row * 2048 + col] = f2bf(acc[mf][nf][i]);
      }
}

// ---- attn pass A: rowsum[h*4+b][q] += sum_{s in tile} exp2(logit) -----------
// grid (64 = qt*4+st, B, H); q-tile 128, s-tile 512 (8 key-steps of 64)
__launch_bounds__(256)
__global__ void k_attn_rs(const unsigned short* __restrict__ qk,
                          const unsigned long long* __restrict__ bits,
                          float* __restrict__ rowsum) {
  __shared__ uint4 k4[1024];                 // K tile 64x128 bf16, 16KB, fragment-order
  __shared__ unsigned long long mw[128];     // mask words, this key-step
  const unsigned short* kl = (const unsigned short*)k4;
  int qt = blockIdx.x >> 2, st = blockIdx.x & 3;
  int b = blockIdx.y, h = blockIdx.z;
  int t = threadIdx.x, w = t >> 6, l = t & 63;
  int lr = l & 15, lc = l >> 4;
  int q0 = qt * 128, sbase = st * 512;
  const unsigned short* Q = qk + (long)b * 4194304 + h * 128;
  const unsigned short* K = qk + (long)b * 4194304 + 1024 + h * 128;
  const unsigned long long* brow = bits + ((long)b * 2048 + q0) * 32;

  short8 qf[2][4];
#pragma unroll
  for (int mf = 0; mf < 2; mf++)
#pragma unroll
    for (int ki = 0; ki < 4; ki++)
      qf[mf][ki] = *(const short8*)(Q + (long)(q0 + w * 32 + mf * 16 + lr) * 2048 + ki * 32 + lc * 8);

  floatx4 z = {0.f, 0.f, 0.f, 0.f};
  float lsum[2][4] = {{0,0,0,0},{0,0,0,0}};

  for (int s0 = sbase; s0 < sbase + 512; s0 += 64) {
    __syncthreads();
#pragma unroll
    for (int j = 0; j < 4; j++) {
      int sub = w * 4 + j, si = sub >> 2, ki = sub & 3;
      gld_lds16(K + (long)(s0 + si * 16 + lr) * 2048 + ki * 32 + lc * 8, k4 + sub * 64);
    }
    if (t < 128) mw[t] = brow[(long)t * 32 + (s0 >> 6)];
    __syncthreads();
    floatx4 acc[2][4];
#pragma unroll
    for (int ii = 0; ii < 2; ii++)
#pragma unroll
      for (int jj = 0; jj < 4; jj++) acc[ii][jj] = z;
#pragma unroll
    for (int ki = 0; ki < 4; ki++) {
      short8 bb[4];
#pragma unroll
      for (int nf = 0; nf < 4; nf++) bb[nf] = *(const short8*)(kl + (nf * 4 + ki) * 512 + l * 8);
#pragma unroll
      for (int nf = 0; nf < 4; nf++) {
        acc[0][nf] = __builtin_amdgcn_mfma_f32_16x16x32_bf16(qf[0][ki], bb[nf], acc[0][nf], 0, 0, 0);
        acc[1][nf] = __builtin_amdgcn_mfma_f32_16x16x32_bf16(qf[1][ki], bb[nf], acc[1][nf], 0, 0, 0);
      }
    }
#pragma unroll
    for (int mf = 0; mf < 2; mf++)
#pragma unroll
      for (int i = 0; i < 4; i++) {
        unsigned long long wmk = mw[w * 32 + mf * 16 + lc * 4 + i] >> lr;
        float p = 0.f;
#pragma unroll
        for (int nf = 0; nf < 4; nf++)
          p += ((wmk >> (nf * 16)) & 1ull) ? 0.f : EXP2(acc[mf][nf][i]);
        lsum[mf][i] += p;
      }
  }
#pragma unroll
  for (int mf = 0; mf < 2; mf++)
#pragma unroll
    for (int i = 0; i < 4; i++) {
      float v = lsum[mf][i];
      v += __shfl_xor(v, 1); v += __shfl_xor(v, 2);
      v += __shfl_xor(v, 4); v += __shfl_xor(v, 8);
      if (lr == 0)
        atomicAdd(&rowsum[((h * 4 + b) << 11) + q0 + w * 32 + mf * 16 + lc * 4 + i], v);
    }
}

// ---- attn pass B: abar[h*4+b][s] += sum_q exp2(logit)/(rowsum_q*2048) -------
__launch_bounds__(256)
__global__ void k_attn_cs(const unsigned short* __restrict__ qk,
                          const unsigned long long* __restrict__ bits,
                          const float* __restrict__ rowsum,
                          float* __restrict__ abar) {
  __shared__ uint4 k4[1024];
  __shared__ unsigned long long mw[128];
  __shared__ float colacc[512];
  const unsigned short* kl = (const unsigned short*)k4;
  int qt = blockIdx.x >> 2, st = blockIdx.x & 3;
  int b = blockIdx.y, h = blockIdx.z;
  int t = threadIdx.x, w = t >> 6, l = t & 63;
  int lr = l & 15, lc = l >> 4;
  int q0 = qt * 128, sbase = st * 512;
  const unsigned short* Q = qk + (long)b * 4194304 + h * 128;
  const unsigned short* K = qk + (long)b * 4194304 + 1024 + h * 128;
  const unsigned long long* brow = bits + ((long)b * 2048 + q0) * 32;

  for (int s = t; s < 512; s += 256) colacc[s] = 0.f;

  short8 qf[2][4];
#pragma unroll
  for (int mf = 0; mf < 2; mf++)
#pragma unroll
    for (int ki = 0; ki < 4; ki++)
      qf[mf][ki] = *(const short8*)(Q + (long)(q0 + w * 32 + mf * 16 + lr) * 2048 + ki * 32 + lc * 8);

  float rinv[2][4];
#pragma unroll
  for (int mf = 0; mf < 2; mf++)
#pragma unroll
    for (int i = 0; i < 4; i++)
      rinv[mf][i] = 1.f / (rowsum[((h * 4 + b) << 11) + q0 + w * 32 + mf * 16 + lc * 4 + i] * 2048.f);

  floatx4 z = {0.f, 0.f, 0.f, 0.f};

  for (int s0 = sbase; s0 < sbase + 512; s0 += 64) {
    __syncthreads();
#pragma unroll
    for (int j = 0; j < 4; j++) {
      int sub = w * 4 + j, si = sub >> 2, ki = sub & 3;
      gld_lds16(K + (long)(s0 + si * 16 + lr) * 2048 + ki * 32 + lc * 8, k4 + sub * 64);
    }
    if (t < 128) mw[t] = brow[(long)t * 32 + (s0 >> 6)];
    __syncthreads();
    floatx4 acc[2][4];
#pragma unroll
    for (int ii = 0; ii < 2; ii++)
#pragma unroll
      for (int jj = 0; jj < 4; jj++) acc[ii][jj] = z;
#pragma unroll
    for (int ki = 0; ki < 4; ki++) {
      short8 bb[4];
#pragma unroll
      for (int nf = 0; nf < 4; nf++) bb[nf] = *(const short8*)(kl + (nf * 4 + ki) * 512 + l * 8);
#pragma unroll
      for (int nf = 0; nf < 4; nf++) {
        acc[0][nf] = __builtin_amdgcn_mfma_f32_16x16x32_bf16(qf[0][ki], bb[nf], acc[0][nf], 0, 0, 0);
        acc[1][nf] = __builtin_amdgcn_mfma_f32_16x16x32_bf16(qf[1][ki], bb[nf], acc[1][nf], 0, 0, 0);
      }
    }
    float cp[4] = {0.f, 0.f, 0.f, 0.f};
#pragma unroll
    for (int mf = 0; mf < 2; mf++)
#pragma unroll
      for (int i = 0; i < 4; i++) {
        unsigned long long wmk = mw[w * 32 + mf * 16 + lc * 4 + i] >> lr;
        float ri = rinv[mf][i];
#pragma unroll
        for (int nf = 0; nf < 4; nf++)
          cp[nf] += ((wmk >> (nf * 16)) & 1ull) ? 0.f : EXP2(acc[mf][nf][i]) * ri;
      }
    int sl = s0 - sbase;
#pragma unroll
    for (int nf = 0; nf < 4; nf++) {
      float v = cp[nf];
      v += __shfl_xor(v, 16);
      v += __shfl_xor(v, 32);
      if (lc == 0) atomicAdd(&colacc[sl + nf * 16 + lr], v);
    }
  }
  __syncthreads();
  float* ab = abar + ((h * 4 + b) << 11) + sbase;
  for (int s = t; s < 512; s += 256) atomicAdd(&ab[s], colacc[s]);
}

// ---- xbar[h*4+b][d] = sum_s abar[h,b,s] * x[b,s,d] -------------------------
__global__ void k_xbar(const float* __restrict__ x, const float* __restrict__ abar,
                       float* __restrict__ xbar) {
  __shared__ float ab[8][128];
  int bx = blockIdx.x;            // dc(4) * 16 + sc(16)
  int b = blockIdx.y;
  int dc = bx >> 4, sc = bx & 15;
  int t = threadIdx.x;
  int d = dc * 256 + t;
  int sc0 = sc * 128;
  for (int i = t; i < 1024; i += 256) {
    int hh = i >> 7, s = i & 127;
    ab[hh][s] = abar[(hh * 4 + b) * 2048 + sc0 + s];
  }
  __syncthreads();
  float acc[8] = {0,0,0,0,0,0,0,0};
  const float* xp = x + ((long)b * 2048 + sc0) * 1024 + d;
  for (int s = 0; s < 128; s++) {
    float xv = xp[(long)s * 1024];
#pragma unroll
    for (int hh = 0; hh < 8; hh++) acc[hh] += xv * ab[hh][s];
  }
#pragma unroll
  for (int hh = 0; hh < 8; hh++) atomicAdd(&xbar[(hh * 4 + b) * 1024 + d], acc[hh]);
}

// ---- ocat[b][h*128+k] = xbar[h,b,:] @ W_v[h][:,k] ---------------------------
__global__ void k_ov(const float* __restrict__ Wv, const float* __restrict__ xbar,
                     float* __restrict__ ocat) {
  __shared__ float xb[1024];
  int hb = blockIdx.x;   // h*4+b
  int h = hb >> 2, b = hb & 3;
  int k = threadIdx.x;   // 128
  for (int i = k; i < 1024; i += 128) xb[i] = xbar[hb * 1024 + i];
  __syncthreads();
  float acc = 0.f;
  const float* wp = Wv + (long)h * 131072 + k;
  for (int d = 0; d < 1024; d++) acc += xb[d] * wp[(long)d * 128];
  ocat[b * 1024 + h * 128 + k] = acc;
}

// ---- out1[b][d] = ocat[b,:] . W_lin[d,:] + b_lin[d] -------------------------
__global__ void k_lin(const float* __restrict__ ocat, const float* __restrict__ Wlin,
                      const float* __restrict__ blin, float* __restrict__ out1) {
  int gw = blockIdx.x * 4 + (threadIdx.x >> 6);   // 0..4095 = b*1024+d
  int l = threadIdx.x & 63;
  int b = gw >> 10, d = gw & 1023;
  const float* o = ocat + b * 1024;
  const float* wr = Wlin + (long)d * 1024;
  float acc = 0.f;
  for (int f = l; f < 1024; f += 64) acc += o[f] * wr[f];
#pragma unroll
  for (int m = 32; m; m >>= 1) acc += __shfl_xor(acc, m);
  if (l == 0) out1[gw] = acc + blin[d];
}

// ---- out[b][c] = out1[b,:] . W_last[c,:] + b_last[c] ------------------------
__global__ void k_last(const float* __restrict__ out1, const float* __restrict__ Wlast,
                       const float* __restrict__ blast, float* __restrict__ out) {
  int gw = blockIdx.x * 4 + (threadIdx.x >> 6);   // 0..511 = b*128+c
  int l = threadIdx.x & 63;
  int b = gw >> 7, c = gw & 127;
  const float* i1 = out1 + b * 1024;
  const float* wr = Wlast + (long)c * 1024;
  float acc = 0.f;
  for (int f = l; f < 1024; f += 64) acc += i1[f] * wr[f];
#pragma unroll
  for (int m = 32; m; m >>= 1) acc += __shfl_xor(acc, m);
  if (l == 0) out[gw] = acc + blast[c];
}

extern "C" void kernel_launch(void* const* d_in, const int* in_sizes, int n_in,
                              void* d_out, int out_size, void* d_ws, size_t ws_size,
                              hipStream_t stream) {
  const float* x     = (const float*)d_in[0];
  const void*  mask  = d_in[1];
  const float* Wq    = (const float*)d_in[2];
  const float* Wk    = (const float*)d_in[3];
  const float* Wv    = (const float*)d_in[4];
  const float* Wlin  = (const float*)d_in[5];
  const float* blin  = (const float*)d_in[6];
  const float* Wlast = (const float*)d_in[7];
  const float* blast = (const float*)d_in[8];
  float* out = (float*)d_out;

  char* ws = (char*)d_ws;
  // ws layout (bytes)
  const size_t OFF_FLAG = 0;                      // 256
  const size_t OFF_BITS = 256;                    // 2,097,152
  const size_t OFF_XBF  = 2097408;                // 16,777,216
  const size_t OFF_WQKT = 18874624;               // 4,194,304
  const size_t OFF_QK   = 23068928;               // 33,554,432
  const size_t OFF_ABAR = 56623360;               // 262,144
  const size_t OFF_XBAR = 56885504;               // 131,072
  const size_t OFF_RSUM = 57016576;               // 262,144
  const size_t OFF_OCAT = 57278720;               // 16,384
  const size_t OFF_OUT1 = 57295104;               // 16,384

  int* flag = (int*)(ws + OFF_FLAG);
  unsigned long long* bits = (unsigned long long*)(ws + OFF_BITS);
  unsigned short* xbf  = (unsigned short*)(ws + OFF_XBF);
  unsigned short* wqkt = (unsigned short*)(ws + OFF_WQKT);
  unsigned short* qkb  = (unsigned short*)(ws + OFF_QK);
  float* abar = (float*)(ws + OFF_ABAR);
  float* xbarp = (float*)(ws + OFF_XBAR);
  float* rsum = (float*)(ws + OFF_RSUM);
  float* ocat = (float*)(ws + OFF_OCAT);
  float* out1 = (float*)(ws + OFF_OUT1);

  hipMemsetAsync(ws + OFF_ABAR, 0, 262144 + 131072 + 262144, stream);  // abar+xbar+rowsum
  k_detect<<<1, 256, 0, stream>>>((const uint32_t*)mask, flag);
  k_bitpack<<<65536, 256, 0, stream>>>(mask, flag, bits);
  k_cvt_x<<<8192, 256, 0, stream>>>((const float4*)x, (uint2*)xbf);
  k_cvt_w<<<8192, 256, 0, stream>>>(Wq, Wk, wqkt);
  k_gemm_qk<<<1024, 256, 0, stream>>>(xbf, wqkt, qkb);
  k_attn_rs<<<dim3(64, 4, 8), 256, 0, stream>>>(qkb, bits, rsum);
  k_attn_cs<<<dim3(64, 4, 8), 256, 0, stream>>>(qkb, bits, rsum, abar);
  k_xbar<<<dim3(64, 4), 256, 0, stream>>>(x, abar, xbarp);
  k_ov<<<32, 128, 0, stream>>>(Wv, xbarp, ocat);
  k_lin<<<1024, 256, 0, stream>>>(ocat, Wlin, blin, out1);
  k_last<<<128, 256, 0, stream>>>(out1, Wlast, blast, out);
}

// Round 4
// 311.577 us; speedup vs baseline: 1.1298x; 1.0537x over previous
//
#include <hip/hip_runtime.h>
#include <stdint.h>

// Problem constants: B=4, S=2048, D=1024, H=8, DK=128, C=128
typedef __attribute__((ext_vector_type(8))) short short8;
typedef __attribute__((ext_vector_type(4))) float floatx4;

#if defined(__has_builtin)
#if __has_builtin(__builtin_amdgcn_exp2f)
#define EXP2(x) __builtin_amdgcn_exp2f(x)
#endif
#endif
#ifndef EXP2
#define EXP2(x) exp2f(x)
#endif

// 1/sqrt(128) * log2(e)  — folded into W_q so softmax needs only v_exp_f32
#define WQ_SCALE (0.08838834764831845f * 1.4426950408889634f)

__device__ __forceinline__ unsigned short f2bf(float f) {
  union { float f; uint32_t u; } v; v.f = f;
  return (unsigned short)((v.u + 0x7fffu + ((v.u >> 16) & 1u)) >> 16);
}

// async global->LDS DMA, 16B per lane; dst is wave-uniform base (+lane*16 implicit)
__device__ __forceinline__ void gld_lds16(const void* g, void* l) {
  __builtin_amdgcn_global_load_lds((const __attribute__((address_space(1))) uint32_t*)g,
                                   (__attribute__((address_space(3))) uint32_t*)l, 16, 0, 0);
}

// ---- detect mask element width (int32 vs uint8) ----------------------------
__global__ void k_detect(const uint32_t* __restrict__ m, int* __restrict__ flag) {
  __shared__ int any;
  if (threadIdx.x == 0) any = 0;
  __syncthreads();
  int a = 0;
  for (int i = threadIdx.x; i < 16384; i += 256) a |= (m[i] > 1u) ? 1 : 0;
  if (a) atomicOr(&any, 1);
  __syncthreads();
  if (threadIdx.x == 0) *flag = any;   // 1 => bytes (uint8/bool), 0 => int32
}

// ---- bit-pack mask: bits[b][q][s/64], bit s = masked ------------------------
__global__ void k_bitpack(const void* __restrict__ mask, const int* __restrict__ flag,
                          unsigned long long* __restrict__ bits) {
  long tid = (long)blockIdx.x * 256 + threadIdx.x;   // (b*2048+q)*2048+s
  int f = *flag;
  int v = f ? (int)((const uint8_t*)mask)[tid] : ((const int*)mask)[tid];
  unsigned long long b = __ballot(v != 0);
  if ((threadIdx.x & 63) == 0) bits[tid >> 6] = b;
}

// ---- x (f32) -> bf16 --------------------------------------------------------
__global__ void k_cvt_x(const float4* __restrict__ x, uint2* __restrict__ xbf) {
  long i = (long)blockIdx.x * 256 + threadIdx.x;
  float4 v = x[i];
  uint2 o;
  o.x = (uint32_t)f2bf(v.x) | ((uint32_t)f2bf(v.y) << 16);
  o.y = (uint32_t)f2bf(v.z) | ((uint32_t)f2bf(v.w) << 16);
  xbf[i] = o;
}

// ---- W_q,W_k [H,D,DK] -> wqkt[2048][1024] bf16; W_q pre-scaled --------------
__global__ void k_cvt_w(const float* __restrict__ wq, const float* __restrict__ wk,
                        unsigned short* __restrict__ wqkt) {
  int tid = blockIdx.x * 256 + threadIdx.x;   // n*1024 + d
  int n = tid >> 10, d = tid & 1023;
  int isq = (n < 1024);
  const float* src = isq ? wq : wk;
  int nn = n & 1023;
  int h = nn >> 7, dk = nn & 127;
  float v = src[h * 131072 + d * 128 + dk];
  wqkt[tid] = f2bf(isq ? v * WQ_SCALE : v);
}

// ---- GEMM: qk[8192][2048] = xbf[8192][1024] * wqkt[2048][1024]^T (bf16 out) -
// Double-buffered LDS staging: stage(k+1) issued before compute(k); one barrier/step.
__launch_bounds__(256, 2)
__global__ void k_gemm_qk(const unsigned short* __restrict__ xbf,
                          const unsigned short* __restrict__ wqkt,
                          unsigned short* __restrict__ qk) {
  __shared__ uint4 ab4[2][2048];   // 2 x 32KB: A subtiles 0..15, B 16..31, fragment-order
  int bx = blockIdx.x;
  bx = (bx & 7) * 128 + (bx >> 3);          // XCD-chunked swizzle (1024 % 8 == 0)
  int m0 = (bx >> 4) * 128, n0 = (bx & 15) * 128;
  int t = threadIdx.x, w = t >> 6, l = t & 63;
  int lr = l & 15, lc = l >> 4;
  int wr = w >> 1, wc = w & 1;
  floatx4 z = {0.f, 0.f, 0.f, 0.f};
  floatx4 acc[4][4];
#pragma unroll
  for (int ii = 0; ii < 4; ii++)
#pragma unroll
    for (int jj = 0; jj < 4; jj++) acc[ii][jj] = z;

  auto stage = [&](int buf, int k0) {
#pragma unroll
    for (int j = 0; j < 8; j++) {
      int s = w * 8 + j;
      const unsigned short* src;
      if (s < 16) { int mi = s >> 1, ki = s & 1;
        src = xbf + (long)(m0 + mi * 16 + lr) * 1024 + k0 + ki * 32 + lc * 8;
      } else { int s2 = s - 16, ni = s2 >> 1, ki = s2 & 1;
        src = wqkt + (long)(n0 + ni * 16 + lr) * 1024 + k0 + ki * 32 + lc * 8;
      }
      gld_lds16(src, &ab4[buf][s * 64]);
    }
  };

  stage(0, 0);
  __syncthreads();
  int cur = 0;
  for (int k0 = 0; k0 < 1024; k0 += 64) {
    if (k0 + 64 < 1024) stage(cur ^ 1, k0 + 64);
    const unsigned short* al = (const unsigned short*)ab4[cur];
    const unsigned short* bl = al + 8192;   // B at byte 16384
#pragma unroll
    for (int ki = 0; ki < 2; ki++) {
      short8 af[4], bfr[4];
#pragma unroll
      for (int mf = 0; mf < 4; mf++)
        af[mf] = *(const short8*)(al + ((wr * 4 + mf) * 2 + ki) * 512 + l * 8);
#pragma unroll
      for (int nf = 0; nf < 4; nf++)
        bfr[nf] = *(const short8*)(bl + ((wc * 4 + nf) * 2 + ki) * 512 + l * 8);
#pragma unroll
      for (int mf = 0; mf < 4; mf++)
#pragma unroll
        for (int nf = 0; nf < 4; nf++)
          acc[mf][nf] = __builtin_amdgcn_mfma_f32_16x16x32_bf16(af[mf], bfr[nf], acc[mf][nf], 0, 0, 0);
    }
    __syncthreads();   // drains vmcnt (next-tile stage) + lgkmcnt (our reads)
    cur ^= 1;
  }
#pragma unroll
  for (int mf = 0; mf < 4; mf++)
#pragma unroll
    for (int nf = 0; nf < 4; nf++)
#pragma unroll
      for (int i = 0; i < 4; i++) {
        int row = m0 + wr * 64 + mf * 16 + lc * 4 + i;
        int col = n0 + wc * 64 + nf * 16 + lr;
        qk[(long)row * 2048 + col] = f2bf(acc[mf][nf][i]);
      }
}

// ---- attn pass A: rowsum[h*4+b][q] += sum_{s in tile} exp2(logit) -----------
// grid (64 = qt*4+st, B, H); q-tile 128, s-tile 512; double-buffered K staging
__launch_bounds__(256)
__global__ void k_attn_rs(const unsigned short* __restrict__ qk,
                          const unsigned long long* __restrict__ bits,
                          float* __restrict__ rowsum) {
  __shared__ uint4 k4[2][1024];              // 2 x 16KB K tile, fragment-order
  __shared__ unsigned long long mw[2][128];  // mask words
  int qt = blockIdx.x >> 2, st = blockIdx.x & 3;
  int b = blockIdx.y, h = blockIdx.z;
  int t = threadIdx.x, w = t >> 6, l = t & 63;
  int lr = l & 15, lc = l >> 4;
  int q0 = qt * 128, sbase = st * 512;
  const unsigned short* Q = qk + (long)b * 4194304 + h * 128;
  const unsigned short* K = qk + (long)b * 4194304 + 1024 + h * 128;
  const unsigned long long* brow = bits + ((long)b * 2048 + q0) * 32;

  auto stageK = [&](int buf, int s0) {
#pragma unroll
    for (int j = 0; j < 4; j++) {
      int sub = w * 4 + j, si = sub >> 2, ki = sub & 3;
      gld_lds16(K + (long)(s0 + si * 16 + lr) * 2048 + ki * 32 + lc * 8, &k4[buf][sub * 64]);
    }
    if (t < 128) mw[buf][t] = brow[(long)t * 32 + (s0 >> 6)];
  };

  short8 qf[2][4];
#pragma unroll
  for (int mf = 0; mf < 2; mf++)
#pragma unroll
    for (int ki = 0; ki < 4; ki++)
      qf[mf][ki] = *(const short8*)(Q + (long)(q0 + w * 32 + mf * 16 + lr) * 2048 + ki * 32 + lc * 8);

  floatx4 z = {0.f, 0.f, 0.f, 0.f};
  float lsum[2][4] = {{0,0,0,0},{0,0,0,0}};

  stageK(0, sbase);
  __syncthreads();
  int cur = 0;
  for (int s0 = sbase; s0 < sbase + 512; s0 += 64) {
    if (s0 + 64 < sbase + 512) stageK(cur ^ 1, s0 + 64);
    const unsigned short* kl = (const unsigned short*)k4[cur];
    floatx4 acc[2][4];
#pragma unroll
    for (int ii = 0; ii < 2; ii++)
#pragma unroll
      for (int jj = 0; jj < 4; jj++) acc[ii][jj] = z;
#pragma unroll
    for (int ki = 0; ki < 4; ki++) {
      short8 bb[4];
#pragma unroll
      for (int nf = 0; nf < 4; nf++) bb[nf] = *(const short8*)(kl + (nf * 4 + ki) * 512 + l * 8);
#pragma unroll
      for (int nf = 0; nf < 4; nf++) {
        acc[0][nf] = __builtin_amdgcn_mfma_f32_16x16x32_bf16(qf[0][ki], bb[nf], acc[0][nf], 0, 0, 0);
        acc[1][nf] = __builtin_amdgcn_mfma_f32_16x16x32_bf16(qf[1][ki], bb[nf], acc[1][nf], 0, 0, 0);
      }
    }
#pragma unroll
    for (int mf = 0; mf < 2; mf++)
#pragma unroll
      for (int i = 0; i < 4; i++) {
        unsigned long long wmk = mw[cur][w * 32 + mf * 16 + lc * 4 + i] >> lr;
        float p = 0.f;
#pragma unroll
        for (int nf = 0; nf < 4; nf++)
          p += ((wmk >> (nf * 16)) & 1ull) ? 0.f : EXP2(acc[mf][nf][i]);
        lsum[mf][i] += p;
      }
    __syncthreads();
    cur ^= 1;
  }
#pragma unroll
  for (int mf = 0; mf < 2; mf++)
#pragma unroll
    for (int i = 0; i < 4; i++) {
      float v = lsum[mf][i];
      v += __shfl_xor(v, 1); v += __shfl_xor(v, 2);
      v += __shfl_xor(v, 4); v += __shfl_xor(v, 8);
      if (lr == 0)
        atomicAdd(&rowsum[((h * 4 + b) << 11) + q0 + w * 32 + mf * 16 + lc * 4 + i], v);
    }
}

// ---- attn pass B: abar[h*4+b][s] += sum_q exp2(logit)/(rowsum_q*2048) -------
__launch_bounds__(256)
__global__ void k_attn_cs(const unsigned short* __restrict__ qk,
                          const unsigned long long* __restrict__ bits,
                          const float* __restrict__ rowsum,
                          float* __restrict__ abar) {
  __shared__ uint4 k4[2][1024];
  __shared__ unsigned long long mw[2][128];
  __shared__ float colacc[512];
  int qt = blockIdx.x >> 2, st = blockIdx.x & 3;
  int b = blockIdx.y, h = blockIdx.z;
  int t = threadIdx.x, w = t >> 6, l = t & 63;
  int lr = l & 15, lc = l >> 4;
  int q0 = qt * 128, sbase = st * 512;
  const unsigned short* Q = qk + (long)b * 4194304 + h * 128;
  const unsigned short* K = qk + (long)b * 4194304 + 1024 + h * 128;
  const unsigned long long* brow = bits + ((long)b * 2048 + q0) * 32;

  for (int s = t; s < 512; s += 256) colacc[s] = 0.f;

  auto stageK = [&](int buf, int s0) {
#pragma unroll
    for (int j = 0; j < 4; j++) {
      int sub = w * 4 + j, si = sub >> 2, ki = sub & 3;
      gld_lds16(K + (long)(s0 + si * 16 + lr) * 2048 + ki * 32 + lc * 8, &k4[buf][sub * 64]);
    }
    if (t < 128) mw[buf][t] = brow[(long)t * 32 + (s0 >> 6)];
  };

  short8 qf[2][4];
#pragma unroll
  for (int mf = 0; mf < 2; mf++)
#pragma unroll
    for (int ki = 0; ki < 4; ki++)
      qf[mf][ki] = *(const short8*)(Q + (long)(q0 + w * 32 + mf * 16 + lr) * 2048 + ki * 32 + lc * 8);

  float rinv[2][4];
#pragma unroll
  for (int mf = 0; mf < 2; mf++)
#pragma unroll
    for (int i = 0; i < 4; i++)
      rinv[mf][i] = 1.f / (rowsum[((h * 4 + b) << 11) + q0 + w * 32 + mf * 16 + lc * 4 + i] * 2048.f);

  floatx4 z = {0.f, 0.f, 0.f, 0.f};

  stageK(0, sbase);
  __syncthreads();
  int cur = 0;
  for (int s0 = sbase; s0 < sbase + 512; s0 += 64) {
    if (s0 + 64 < sbase + 512) stageK(cur ^ 1, s0 + 64);
    const unsigned short* kl = (const unsigned short*)k4[cur];
    floatx4 acc[2][4];
#pragma unroll
    for (int ii = 0; ii < 2; ii++)
#pragma unroll
      for (int jj = 0; jj < 4; jj++) acc[ii][jj] = z;
#pragma unroll
    for (int ki = 0; ki < 4; ki++) {
      short8 bb[4];
#pragma unroll
      for (int nf = 0; nf < 4; nf++) bb[nf] = *(const short8*)(kl + (nf * 4 + ki) * 512 + l * 8);
#pragma unroll
      for (int nf = 0; nf < 4; nf++) {
        acc[0][nf] = __builtin_amdgcn_mfma_f32_16x16x32_bf16(qf[0][ki], bb[nf], acc[0][nf], 0, 0, 0);
        acc[1][nf] = __builtin_amdgcn_mfma_f32_16x16x32_bf16(qf[1][ki], bb[nf], acc[1][nf], 0, 0, 0);
      }
    }
    float cp[4] = {0.f, 0.f, 0.f, 0.f};
#pragma unroll
    for (int mf = 0; mf < 2; mf++)
#pragma unroll
      for (int i = 0; i < 4; i++) {
        unsigned long long wmk = mw[cur][w * 32 + mf * 16 + lc * 4 + i] >> lr;
        float ri = rinv[mf][i];
#pragma unroll
        for (int nf = 0; nf < 4; nf++)
          cp[nf] += ((wmk >> (nf * 16)) & 1ull) ? 0.f : EXP2(acc[mf][nf][i]) * ri;
      }
    int sl = s0 - sbase;
#pragma unroll
    for (int nf = 0; nf < 4; nf++) {
      float v = cp[nf];
      v += __shfl_xor(v, 16);
      v += __shfl_xor(v, 32);
      if (lc == 0) atomicAdd(&colacc[sl + nf * 16 + lr], v);
    }
    __syncthreads();
    cur ^= 1;
  }
  __syncthreads();
  float* ab = abar + ((h * 4 + b) << 11) + sbase;
  for (int s = t; s < 512; s += 256) atomicAdd(&ab[s], colacc[s]);
}

// ---- xbar[h*4+b][d] = sum_s abar[h,b,s] * x[b,s,d] -------------------------
__global__ void k_xbar(const float* __restrict__ x, const float* __restrict__ abar,
                       float* __restrict__ xbar) {
  __shared__ float ab[8][128];
  int bx = blockIdx.x;            // dc(4) * 16 + sc(16)
  int b = blockIdx.y;
  int dc = bx >> 4, sc = bx & 15;
  int t = threadIdx.x;
  int d = dc * 256 + t;
  int sc0 = sc * 128;
  for (int i = t; i < 1024; i += 256) {
    int hh = i >> 7, s = i & 127;
    ab[hh][s] = abar[(hh * 4 + b) * 2048 + sc0 + s];
  }
  __syncthreads();
  float acc[8] = {0,0,0,0,0,0,0,0};
  const float* xp = x + ((long)b * 2048 + sc0) * 1024 + d;
  for (int s = 0; s < 128; s++) {
    float xv = xp[(long)s * 1024];
#pragma unroll
    for (int hh = 0; hh < 8; hh++) acc[hh] += xv * ab[hh][s];
  }
#pragma unroll
  for (int hh = 0; hh < 8; hh++) atomicAdd(&xbar[(hh * 4 + b) * 1024 + d], acc[hh]);
}

// ---- ocat[b][h*128+k] = xbar[h,b,:] @ W_v[h][:,k] ---------------------------
__global__ void k_ov(const float* __restrict__ Wv, const float* __restrict__ xbar,
                     float* __restrict__ ocat) {
  __shared__ float xb[1024];
  int hb = blockIdx.x;   // h*4+b
  int h = hb >> 2, b = hb & 3;
  int k = threadIdx.x;   // 128
  for (int i = k; i < 1024; i += 128) xb[i] = xbar[hb * 1024 + i];
  __syncthreads();
  float acc = 0.f;
  const float* wp = Wv + (long)h * 131072 + k;
  for (int d = 0; d < 1024; d++) acc += xb[d] * wp[(long)d * 128];
  ocat[b * 1024 + h * 128 + k] = acc;
}

// ---- out1[b][d] = ocat[b,:] . W_lin[d,:] + b_lin[d] -------------------------
__global__ void k_lin(const float* __restrict__ ocat, const float* __restrict__ Wlin,
                      const float* __restrict__ blin, float* __restrict__ out1) {
  int gw = blockIdx.x * 4 + (threadIdx.x >> 6);   // 0..4095 = b*1024+d
  int l = threadIdx.x & 63;
  int b = gw >> 10, d = gw & 1023;
  const float* o = ocat + b * 1024;
  const float* wr = Wlin + (long)d * 1024;
  float acc = 0.f;
  for (int f = l; f < 1024; f += 64) acc += o[f] * wr[f];
#pragma unroll
  for (int m = 32; m; m >>= 1) acc += __shfl_xor(acc, m);
  if (l == 0) out1[gw] = acc + blin[d];
}

// ---- out[b][c] = out1[b,:] . W_last[c,:] + b_last[c] ------------------------
__global__ void k_last(const float* __restrict__ out1, const float* __restrict__ Wlast,
                       const float* __restrict__ blast, float* __restrict__ out) {
  int gw = blockIdx.x * 4 + (threadIdx.x >> 6);   // 0..511 = b*128+c
  int l = threadIdx.x & 63;
  int b = gw >> 7, c = gw & 127;
  const float* i1 = out1 + b * 1024;
  const float* wr = Wlast + (long)c * 1024;
  float acc = 0.f;
  for (int f = l; f < 1024; f += 64) acc += i1[f] * wr[f];
#pragma unroll
  for (int m = 32; m; m >>= 1) acc += __shfl_xor(acc, m);
  if (l == 0) out[gw] = acc + blast[c];
}

extern "C" void kernel_launch(void* const* d_in, const int* in_sizes, int n_in,
                              void* d_out, int out_size, void* d_ws, size_t ws_size,
                              hipStream_t stream) {
  const float* x     = (const float*)d_in[0];
  const void*  mask  = d_in[1];
  const float* Wq    = (const float*)d_in[2];
  const float* Wk    = (const float*)d_in[3];
  const float* Wv    = (const float*)d_in[4];
  const float* Wlin  = (const float*)d_in[5];
  const float* blin  = (const float*)d_in[6];
  const float* Wlast = (const float*)d_in[7];
  const float* blast = (const float*)d_in[8];
  float* out = (float*)d_out;

  char* ws = (char*)d_ws;
  // ws layout (bytes)
  const size_t OFF_FLAG = 0;                      // 256
  const size_t OFF_BITS = 256;                    // 2,097,152
  const size_t OFF_XBF  = 2097408;                // 16,777,216
  const size_t OFF_WQKT = 18874624;               // 4,194,304
  const size_t OFF_QK   = 23068928;               // 33,554,432
  const size_t OFF_ABAR = 56623360;               // 262,144
  const size_t OFF_XBAR = 56885504;               // 131,072
  const size_t OFF_RSUM = 57016576;               // 262,144
  const size_t OFF_OCAT = 57278720;               // 16,384
  const size_t OFF_OUT1 = 57295104;               // 16,384

  int* flag = (int*)(ws + OFF_FLAG);
  unsigned long long* bits = (unsigned long long*)(ws + OFF_BITS);
  unsigned short* xbf  = (unsigned short*)(ws + OFF_XBF);
  unsigned short* wqkt = (unsigned short*)(ws + OFF_WQKT);
  unsigned short* qkb  = (unsigned short*)(ws + OFF_QK);
  float* abar = (float*)(ws + OFF_ABAR);
  float* xbarp = (float*)(ws + OFF_XBAR);
  float* rsum = (float*)(ws + OFF_RSUM);
  float* ocat = (float*)(ws + OFF_OCAT);
  float* out1 = (float*)(ws + OFF_OUT1);

  hipMemsetAsync(ws + OFF_ABAR, 0, 262144 + 131072 + 262144, stream);  // abar+xbar+rowsum
  k_detect<<<1, 256, 0, stream>>>((const uint32_t*)mask, flag);
  k_bitpack<<<65536, 256, 0, stream>>>(mask, flag, bits);
  k_cvt_x<<<8192, 256, 0, stream>>>((const float4*)x, (uint2*)xbf);
  k_cvt_w<<<8192, 256, 0, stream>>>(Wq, Wk, wqkt);
  k_gemm_qk<<<1024, 256, 0, stream>>>(xbf, wqkt, qkb);
  k_attn_rs<<<dim3(64, 4, 8), 256, 0, stream>>>(qkb, bits, rsum);
  k_attn_cs<<<dim3(64, 4, 8), 256, 0, stream>>>(qkb, bits, rsum, abar);
  k_xbar<<<dim3(64, 4), 256, 0, stream>>>(x, abar, xbarp);
  k_ov<<<32, 128, 0, stream>>>(Wv, xbarp, ocat);
  k_lin<<<1024, 256, 0, stream>>>(ocat, Wlin, blin, out1);
  k_last<<<128, 256, 0, stream>>>(out1, Wlast, blast, out);
}